// Round 3
// baseline (239.973 us; speedup 1.0000x reference)
//
#include <hip/hip_runtime.h>
#include <hip/hip_bf16.h>

#define B_ 32
#define N_ 512
#define H_ 128

typedef float f32x4 __attribute__((ext_vector_type(4)));
typedef short short8 __attribute__((ext_vector_type(8)));
typedef short short4v __attribute__((ext_vector_type(4)));

static __device__ __forceinline__ float bf2f(unsigned short u) {
  union { unsigned int ui; float f; } x;
  x.ui = ((unsigned int)u) << 16;
  return x.f;
}
static __device__ __forceinline__ unsigned short f2bf(float f) {
  __hip_bfloat16 h = __float2bfloat16(f);
  return *reinterpret_cast<unsigned short*>(&h);
}

// -------------------------------------------------------------------------
// Kernel 1: h[b,n,d] = silu(LN(s[b,n,:] @ W1[d,:] + b1[d]))
// stored TRANSPOSED bf16 into ws:  h_t[b][d][n].
// -------------------------------------------------------------------------
__global__ __launch_bounds__(256) void lin_ln_silu_kernel(
    const float* __restrict__ s, const float* __restrict__ W1,
    const float* __restrict__ b1, unsigned short* __restrict__ h_t) {
  __shared__ float s_sh[32 * 132];            // [n][k] fp32, pad 132
  __shared__ unsigned short w_sh[128 * 132];  // [d][k] bf16, pad 132
  __shared__ unsigned short ht_sh[128 * 40];  // [d][n] bf16, pad 40
  const int t = threadIdx.x;
  const int b = blockIdx.y;
  const int n0 = blockIdx.x * 32;

#pragma unroll
  for (int r = 0; r < 16; ++r) {
    int q = t + 256 * r;
    int d = q >> 5, part = q & 31;
    float4 v = *reinterpret_cast<const float4*>(W1 + d * H_ + part * 4);
    short4v w;
    w.x = (short)f2bf(v.x); w.y = (short)f2bf(v.y);
    w.z = (short)f2bf(v.z); w.w = (short)f2bf(v.w);
    *reinterpret_cast<short4v*>(&w_sh[d * 132 + part * 4]) = w;
  }
#pragma unroll
  for (int r = 0; r < 4; ++r) {
    int q = t + 256 * r;
    int n = q >> 5, part = q & 31;
    float4 v = *reinterpret_cast<const float4*>(
        s + ((size_t)b * N_ + n0 + n) * H_ + part * 4);
    *reinterpret_cast<float4*>(&s_sh[n * 132 + part * 4]) = v;
  }
  __syncthreads();

  const int a = t & 15;
  const int g = t >> 4;
  float acc[2][8];
#pragma unroll
  for (int nn = 0; nn < 2; ++nn)
#pragma unroll
    for (int dd = 0; dd < 8; ++dd) acc[nn][dd] = 0.f;

  float bias[8];
#pragma unroll
  for (int dd = 0; dd < 8; ++dd) bias[dd] = b1[dd * 16 + a];

  for (int k = 0; k < 128; k += 4) {
    float wf[8][4];
#pragma unroll
    for (int dd = 0; dd < 8; ++dd) {
      short4v wv =
          *reinterpret_cast<const short4v*>(&w_sh[(dd * 16 + a) * 132 + k]);
      wf[dd][0] = bf2f((unsigned short)wv.x);
      wf[dd][1] = bf2f((unsigned short)wv.y);
      wf[dd][2] = bf2f((unsigned short)wv.z);
      wf[dd][3] = bf2f((unsigned short)wv.w);
    }
#pragma unroll
    for (int nn = 0; nn < 2; ++nn) {
      float4 sv =
          *reinterpret_cast<const float4*>(&s_sh[(nn * 16 + g) * 132 + k]);
#pragma unroll
      for (int dd = 0; dd < 8; ++dd) {
        acc[nn][dd] += sv.x * wf[dd][0] + sv.y * wf[dd][1] +
                       sv.z * wf[dd][2] + sv.w * wf[dd][3];
      }
    }
  }

#pragma unroll
  for (int nn = 0; nn < 2; ++nn) {
    float s1 = 0.f, s2 = 0.f;
#pragma unroll
    for (int dd = 0; dd < 8; ++dd) {
      float x = acc[nn][dd] + bias[dd];
      acc[nn][dd] = x;
      s1 += x;
      s2 += x * x;
    }
#pragma unroll
    for (int off = 8; off >= 1; off >>= 1) {
      s1 += __shfl_xor(s1, off);
      s2 += __shfl_xor(s2, off);
    }
    float mean = s1 * (1.f / 128.f);
    float var = s2 * (1.f / 128.f) - mean * mean;
    float rs = rsqrtf(var + 1e-5f);
#pragma unroll
    for (int dd = 0; dd < 8; ++dd) {
      float x = (acc[nn][dd] - mean) * rs;
      float y = x / (1.f + __expf(-x));  // silu
      ht_sh[(dd * 16 + a) * 40 + nn * 16 + g] = f2bf(y);
    }
  }
  __syncthreads();

#pragma unroll
  for (int r = 0; r < 2; ++r) {
    int q = t + 256 * r;
    int d = q >> 2, part = q & 3;
    float4 v = *reinterpret_cast<const float4*>(&ht_sh[d * 40 + part * 8]);
    *reinterpret_cast<float4*>(
        h_t + ((size_t)b * 128 + d) * 512 + n0 + part * 8) = v;
  }
}

// -------------------------------------------------------------------------
// Kernel 2: v[b,i,c,d] = sum_j mask*ev*h via MFMA, SOFTWARE-PIPELINED.
// Geometry as R2: grid (2, N/16, B) = 2048 blocks, 128 thr (2 waves),
// block = (b, 16 i, 64 d). Pipeline: loads for round r+1 issued (to VGPRs)
// before the barrier of round r -> a full 24 KB burst stays in flight per
// block at all times. LDS double-buffered (pitch 68), ONE barrier per round:
//   wave order: wait L(r) -> convert/ds_write buf[r&1] -> issue L(r+1)
//               -> barrier(r) -> MFMA on buf[r&1]
// safety: round r+2's writes to buf[r&1] occur after barrier(r+1), which a
// wave passes only after every wave finished MFMA(r) (MFMA precedes the
// r+1 conversion in program order).
// -------------------------------------------------------------------------
#define PITCH 68  // shorts; 34 dwords -> b128 frag reads ~2-way (free)

struct Stage {
  float4 hh[4];     // 4x (8 bf16) h_t chunks
  float4 e[2][3];   // 2 tasks x 12 ev floats
  float4 m[2];      // 2 tasks x 4 mask floats
};

__global__ __launch_bounds__(128) void cfconv_mfma_kernel(
    const float* __restrict__ ev, const float* __restrict__ mask,
    const unsigned short* __restrict__ h_t, float* __restrict__ out) {
  __shared__ unsigned short ph[2][48 * PITCH];  // [m=c*16+i][j]
  __shared__ unsigned short hh[2][64 * PITCH];  // [d][j]
  const int t = threadIdx.x;
  const int dhalf = blockIdx.x * 64;
  const int i0 = blockIdx.y * 16;
  const int b = blockIdx.z;
  const int lane = t & 63;
  const int w = t >> 6;
  const int l15 = lane & 15;
  const int quad = lane >> 4;

  // per-thread staging geometry (fixed across rounds; only j0 moves)
  const int hd = t >> 3;        // hh: d-row 0..15 (+16 per rep)
  const int hp8 = t & 7;        //     8-j chunk
  const int ti[2] = {t >> 4, (t + 128) >> 4};  // task i (0..15)
  const int tj[2] = {(t & 15) * 4, (t & 15) * 4};
  const unsigned short* hbase =
      h_t + ((size_t)b * 128 + dhalf) * 512;  // + d*512 + j
  const float* evbase = ev + ((size_t)(b * N_ + i0) * N_) * 3;  // + (i*512+j)*3
  const float* mbase = mask + (size_t)(b * N_ + i0) * N_;       // + i*512 + j

  Stage st[2];

  auto load_stage = [&](Stage& s_, int j0) {
#pragma unroll
    for (int r = 0; r < 4; ++r) {
      int d = hd + 16 * r;
      s_.hh[r] = *reinterpret_cast<const float4*>(hbase + d * 512 + j0 + hp8 * 8);
    }
#pragma unroll
    for (int tk = 0; tk < 2; ++tk) {
      const float* eb = evbase + ((size_t)ti[tk] * N_ + j0 + tj[tk]) * 3;
      s_.e[tk][0] = *reinterpret_cast<const float4*>(eb);
      s_.e[tk][1] = *reinterpret_cast<const float4*>(eb + 4);
      s_.e[tk][2] = *reinterpret_cast<const float4*>(eb + 8);
      s_.m[tk] = *reinterpret_cast<const float4*>(mbase + ti[tk] * N_ + j0 + tj[tk]);
    }
  };

  auto write_stage = [&](const Stage& s_, int buf) {
#pragma unroll
    for (int r = 0; r < 4; ++r) {
      int d = hd + 16 * r;
      *reinterpret_cast<float4*>(&hh[buf][d * PITCH + hp8 * 8]) = s_.hh[r];
    }
#pragma unroll
    for (int tk = 0; tk < 2; ++tk) {
      float f[12] = {s_.e[tk][0].x, s_.e[tk][0].y, s_.e[tk][0].z, s_.e[tk][0].w,
                     s_.e[tk][1].x, s_.e[tk][1].y, s_.e[tk][1].z, s_.e[tk][1].w,
                     s_.e[tk][2].x, s_.e[tk][2].y, s_.e[tk][2].z, s_.e[tk][2].w};
      float mm[4] = {s_.m[tk].x, s_.m[tk].y, s_.m[tk].z, s_.m[tk].w};
#pragma unroll
      for (int c = 0; c < 3; ++c) {
        short4v wv;
        wv.x = (short)f2bf(f[0 * 3 + c] * mm[0]);
        wv.y = (short)f2bf(f[1 * 3 + c] * mm[1]);
        wv.z = (short)f2bf(f[2 * 3 + c] * mm[2]);
        wv.w = (short)f2bf(f[3 * 3 + c] * mm[3]);
        *reinterpret_cast<short4v*>(&ph[buf][(c * 16 + ti[tk]) * PITCH + tj[tk]]) = wv;
      }
    }
  };

  f32x4 acc[3][2];
#pragma unroll
  for (int mt = 0; mt < 3; ++mt)
#pragma unroll
    for (int nt = 0; nt < 2; ++nt)
#pragma unroll
      for (int e = 0; e < 4; ++e) acc[mt][nt][e] = 0.f;

  load_stage(st[0], 0);

#pragma unroll
  for (int r = 0; r < 8; ++r) {
    const int cur = r & 1;
    write_stage(st[cur], cur);          // waits vmcnt for L(r) only
    if (r < 7) load_stage(st[cur ^ 1], (r + 1) * 64);  // burst in flight
    __syncthreads();                    // buf[cur] ready for all waves

#pragma unroll
    for (int ks = 0; ks < 2; ++ks) {
      short8 av[3], bv[2];
#pragma unroll
      for (int mt = 0; mt < 3; ++mt)
        av[mt] = *reinterpret_cast<const short8*>(
            &ph[cur][(mt * 16 + l15) * PITCH + ks * 32 + quad * 8]);
#pragma unroll
      for (int nt = 0; nt < 2; ++nt) {
        int d = w * 32 + nt * 16 + l15;
        bv[nt] = *reinterpret_cast<const short8*>(
            &hh[cur][d * PITCH + ks * 32 + quad * 8]);
      }
#pragma unroll
      for (int mt = 0; mt < 3; ++mt)
#pragma unroll
        for (int nt = 0; nt < 2; ++nt)
          acc[mt][nt] = __builtin_amdgcn_mfma_f32_16x16x32_bf16(
              av[mt], bv[nt], acc[mt][nt], 0, 0, 0);
    }
    // no second barrier: next round writes the other buffer; see header note
  }

  // epilogue: C/D layout col=lane&15 (d), row=quad*4+reg (il); c = mt
#pragma unroll
  for (int mt = 0; mt < 3; ++mt) {
#pragma unroll
    for (int nt = 0; nt < 2; ++nt) {
      int d = dhalf + w * 32 + nt * 16 + l15;
#pragma unroll
      for (int r = 0; r < 4; ++r) {
        int i = i0 + quad * 4 + r;
        out[(((size_t)b * N_ + i) * 3 + mt) * H_ + d] = acc[mt][nt][r];
      }
    }
  }
}

extern "C" void kernel_launch(void* const* d_in, const int* in_sizes, int n_in,
                              void* d_out, int out_size, void* d_ws,
                              size_t ws_size, hipStream_t stream) {
  const float* s = (const float*)d_in[0];
  const float* ev = (const float*)d_in[1];
  const float* mask = (const float*)d_in[2];
  const float* W1 = (const float*)d_in[3];
  const float* b1 = (const float*)d_in[4];
  float* out = (float*)d_out;
  unsigned short* h_t = (unsigned short*)d_ws;  // bf16 [B][128][512] = 4 MB

  lin_ln_silu_kernel<<<dim3(N_ / 32, B_), 256, 0, stream>>>(s, W1, b1, h_t);
  cfconv_mfma_kernel<<<dim3(2, N_ / 16, B_), 128, 0, stream>>>(ev, mask, h_t,
                                                               out);
}

// Round 4
// 229.336 us; speedup vs baseline: 1.0464x; 1.0464x over previous
//
#include <hip/hip_runtime.h>
#include <hip/hip_bf16.h>

#define B_ 32
#define N_ 512
#define H_ 128

typedef float f32x4 __attribute__((ext_vector_type(4)));
typedef short short8 __attribute__((ext_vector_type(8)));

static __device__ __forceinline__ unsigned short f2bf(float f) {
  __hip_bfloat16 h = __float2bfloat16(f);
  return *reinterpret_cast<unsigned short*>(&h);
}
static __device__ __forceinline__ short8 pack8(float a0, float a1, float a2,
                                               float a3, float a4, float a5,
                                               float a6, float a7) {
  short8 v;
  v[0] = (short)f2bf(a0); v[1] = (short)f2bf(a1);
  v[2] = (short)f2bf(a2); v[3] = (short)f2bf(a3);
  v[4] = (short)f2bf(a4); v[5] = (short)f2bf(a5);
  v[6] = (short)f2bf(a6); v[7] = (short)f2bf(a7);
  return v;
}

// -------------------------------------------------------------------------
// Kernel 1: h[b,n,d] = silu(LN(s[b,n,:] @ W1[d,:] + b1[d])), MFMA version.
// One wave per (b, 16-n tile). A = s rows (m=n, k), B = W1 rows (n-dim=d,
// k-major, fp32->bf16 on the fly, L2-hot). acc: 8 nt x f32x4.
// LN: lane holds n=quad*4+r, d=nt*16+l15 -> sum over nt regs then
// shfl_xor(1,2,4,8) across l15. Output transposed via 4 KB LDS ->
// h_t[b][d][n] bf16 (16 B chunks).
// -------------------------------------------------------------------------
__global__ __launch_bounds__(64) void lin_ln_silu_kernel(
    const float* __restrict__ s, const float* __restrict__ W1,
    const float* __restrict__ b1, unsigned short* __restrict__ h_t) {
  __shared__ unsigned short trans[128 * 16];  // [d][n_local]
  const int t = threadIdx.x;
  const int n0 = blockIdx.x * 16;
  const int b = blockIdx.y;
  const int l15 = t & 15;
  const int quad = t >> 4;

  f32x4 acc[8];
#pragma unroll
  for (int nt = 0; nt < 8; ++nt)
#pragma unroll
    for (int e = 0; e < 4; ++e) acc[nt][e] = 0.f;

  const float* srow = s + ((size_t)b * N_ + n0 + l15) * H_;

#pragma unroll
  for (int ks = 0; ks < 4; ++ks) {
    const int k = ks * 32 + quad * 8;
    float4 a0 = *reinterpret_cast<const float4*>(srow + k);
    float4 a1 = *reinterpret_cast<const float4*>(srow + k + 4);
    short8 av = pack8(a0.x, a0.y, a0.z, a0.w, a1.x, a1.y, a1.z, a1.w);
#pragma unroll
    for (int nt = 0; nt < 8; ++nt) {
      const float* wrow = W1 + (size_t)(nt * 16 + l15) * H_ + k;
      float4 w0 = *reinterpret_cast<const float4*>(wrow);
      float4 w1 = *reinterpret_cast<const float4*>(wrow + 4);
      short8 bv = pack8(w0.x, w0.y, w0.z, w0.w, w1.x, w1.y, w1.z, w1.w);
      acc[nt] = __builtin_amdgcn_mfma_f32_16x16x32_bf16(av, bv, acc[nt], 0, 0, 0);
    }
  }

  float bb[8];
#pragma unroll
  for (int nt = 0; nt < 8; ++nt) bb[nt] = b1[nt * 16 + l15];

#pragma unroll
  for (int r = 0; r < 4; ++r) {
    float s1 = 0.f, s2 = 0.f;
#pragma unroll
    for (int nt = 0; nt < 8; ++nt) {
      float x = acc[nt][r] + bb[nt];
      acc[nt][r] = x;
      s1 += x;
      s2 += x * x;
    }
#pragma unroll
    for (int off = 8; off >= 1; off >>= 1) {
      s1 += __shfl_xor(s1, off);
      s2 += __shfl_xor(s2, off);
    }
    float mean = s1 * (1.f / 128.f);
    float var = s2 * (1.f / 128.f) - mean * mean;
    float rs = rsqrtf(var + 1e-5f);
#pragma unroll
    for (int nt = 0; nt < 8; ++nt) {
      float x = (acc[nt][r] - mean) * rs;
      float y = x / (1.f + __expf(-x));  // silu
      trans[(nt * 16 + l15) * 16 + quad * 4 + r] = f2bf(y);
    }
  }
  __syncthreads();

#pragma unroll
  for (int r2 = 0; r2 < 2; ++r2) {
    int d = t + 64 * r2;
    unsigned short* dst = h_t + ((size_t)b * H_ + d) * N_ + n0;
    short8 v0 = *reinterpret_cast<const short8*>(&trans[d * 16]);
    short8 v1 = *reinterpret_cast<const short8*>(&trans[d * 16 + 8]);
    *reinterpret_cast<short8*>(dst) = v0;
    *reinterpret_cast<short8*>(dst + 8) = v1;
  }
}

// -------------------------------------------------------------------------
// Kernel 2: v[b,i,c,d] = sum_j mask*ev*h. WAVE-STANDALONE: no LDS, no
// barriers. One wave per (i-tile of 16, d-half of 64, b).
// Per 32-j slab: lane(l15=i, quad=k-group) loads its own ev (6x float4,
// 96 B contiguous) + mask (2x float4), packs A-frags av[c] in registers;
// B-frags bv[nt] load 16 B straight from h_t (L2-hot). 12 MFMA/slab,
// 16 slabs, full unroll -> compiler pipelines loads across slabs freely
// (no vmcnt(0) drains anywhere in the loop).
// Grid (32 i-tiles, 2 dh, 32 b): dh-twins are 32 apart in linear id
// = same XCD (mod 8) -> ev/mask HBM-fetched once, twin hits L2.
// -------------------------------------------------------------------------
__global__ __launch_bounds__(64, 2) void cfconv_mfma_kernel(
    const float* __restrict__ ev, const float* __restrict__ mask,
    const unsigned short* __restrict__ h_t, float* __restrict__ out) {
  const int t = threadIdx.x;
  const int i0 = blockIdx.x * 16;
  const int dh = blockIdx.y * 64;
  const int b = blockIdx.z;
  const int l15 = t & 15;
  const int quad = t >> 4;

  const float* evrow = ev + ((size_t)(b * N_ + i0 + l15) * N_) * 3;  // +j*3
  const float* mrow = mask + (size_t)(b * N_ + i0 + l15) * N_;       // +j
  const unsigned short* hrow = h_t + ((size_t)b * H_ + dh) * N_;     // +dl*512+j

  f32x4 acc[3][4];
#pragma unroll
  for (int c = 0; c < 3; ++c)
#pragma unroll
    for (int nt = 0; nt < 4; ++nt)
#pragma unroll
      for (int e = 0; e < 4; ++e) acc[c][nt][e] = 0.f;

#pragma unroll
  for (int sl = 0; sl < 16; ++sl) {
    const int j0 = sl * 32 + quad * 8;  // this lane's 8-j group

    float4 e0 = *reinterpret_cast<const float4*>(evrow + j0 * 3);
    float4 e1 = *reinterpret_cast<const float4*>(evrow + j0 * 3 + 4);
    float4 e2 = *reinterpret_cast<const float4*>(evrow + j0 * 3 + 8);
    float4 e3 = *reinterpret_cast<const float4*>(evrow + j0 * 3 + 12);
    float4 e4 = *reinterpret_cast<const float4*>(evrow + j0 * 3 + 16);
    float4 e5 = *reinterpret_cast<const float4*>(evrow + j0 * 3 + 20);
    float4 m0 = *reinterpret_cast<const float4*>(mrow + j0);
    float4 m1 = *reinterpret_cast<const float4*>(mrow + j0 + 4);

    short8 bv[4];
#pragma unroll
    for (int nt = 0; nt < 4; ++nt)
      bv[nt] = *reinterpret_cast<const short8*>(
          hrow + (size_t)(nt * 16 + l15) * N_ + j0);

    // f[e*3+c] = ev[j0+e][c]; mk[e] = mask[j0+e]
    const float f0 = e0.x, f1 = e0.y, f2 = e0.z, f3 = e0.w;
    const float f4 = e1.x, f5 = e1.y, f6 = e1.z, f7 = e1.w;
    const float f8 = e2.x, f9 = e2.y, f10 = e2.z, f11 = e2.w;
    const float f12 = e3.x, f13 = e3.y, f14 = e3.z, f15 = e3.w;
    const float f16 = e4.x, f17 = e4.y, f18 = e4.z, f19 = e4.w;
    const float f20 = e5.x, f21 = e5.y, f22 = e5.z, f23 = e5.w;
    const float k0 = m0.x, k1 = m0.y, k2 = m0.z, k3 = m0.w;
    const float k4 = m1.x, k5 = m1.y, k6 = m1.z, k7 = m1.w;

    short8 av[3];
    av[0] = pack8(f0 * k0, f3 * k1, f6 * k2, f9 * k3, f12 * k4, f15 * k5,
                  f18 * k6, f21 * k7);
    av[1] = pack8(f1 * k0, f4 * k1, f7 * k2, f10 * k3, f13 * k4, f16 * k5,
                  f19 * k6, f22 * k7);
    av[2] = pack8(f2 * k0, f5 * k1, f8 * k2, f11 * k3, f14 * k4, f17 * k5,
                  f20 * k6, f23 * k7);

#pragma unroll
    for (int c = 0; c < 3; ++c)
#pragma unroll
      for (int nt = 0; nt < 4; ++nt)
        acc[c][nt] = __builtin_amdgcn_mfma_f32_16x16x32_bf16(av[c], bv[nt],
                                                             acc[c][nt], 0, 0, 0);
  }

  // epilogue: C/D layout col=lane&15 (d_local), row=quad*4+reg (i_local)
#pragma unroll
  for (int c = 0; c < 3; ++c)
#pragma unroll
    for (int nt = 0; nt < 4; ++nt) {
      const int d = dh + nt * 16 + l15;
#pragma unroll
      for (int r = 0; r < 4; ++r) {
        const int i = i0 + quad * 4 + r;
        out[(((size_t)b * N_ + i) * 3 + c) * H_ + d] = acc[c][nt][r];
      }
    }
}

extern "C" void kernel_launch(void* const* d_in, const int* in_sizes, int n_in,
                              void* d_out, int out_size, void* d_ws,
                              size_t ws_size, hipStream_t stream) {
  const float* s = (const float*)d_in[0];
  const float* ev = (const float*)d_in[1];
  const float* mask = (const float*)d_in[2];
  const float* W1 = (const float*)d_in[3];
  const float* b1 = (const float*)d_in[4];
  float* out = (float*)d_out;
  unsigned short* h_t = (unsigned short*)d_ws;  // bf16 [B][128][512] = 4 MB

  lin_ln_silu_kernel<<<dim3(N_ / 16, B_), 64, 0, stream>>>(s, W1, b1, h_t);
  cfconv_mfma_kernel<<<dim3(N_ / 16, 2, B_), 64, 0, stream>>>(ev, mask, h_t,
                                                              out);
}

// Round 5
// 219.472 us; speedup vs baseline: 1.0934x; 1.0449x over previous
//
#include <hip/hip_runtime.h>
#include <hip/hip_bf16.h>

#define B_ 32
#define N_ 512
#define H_ 128

typedef float f32x4 __attribute__((ext_vector_type(4)));
typedef short short8 __attribute__((ext_vector_type(8)));
typedef short short4v __attribute__((ext_vector_type(4)));

static __device__ __forceinline__ unsigned short f2bf(float f) {
  __hip_bfloat16 h = __float2bfloat16(f);
  return *reinterpret_cast<unsigned short*>(&h);
}

// hfrag layout (bf16 shorts): [b][NT(8)][KS(16)][lane(64)][e(8)]
//   element (d, j):  NT=d>>4, KS=j>>5, lane=((j>>3)&3)*16 + (d&15), e=j&7
// A B-frag load for mfma_f32_16x16x32_bf16 (n=d tile NT, k-slab KS) is then
// ONE contiguous 1KB wave load: lane L reads 16B at base + L*16.

// -------------------------------------------------------------------------
// Kernel 1: h = silu(LN(s @ W1^T + b1)) -> hfrag (frag-major bf16).
// Grid (N/32, B), 256 thr (4 waves). MFMA GEMM: M=32 n-rows, N=128 d, K=128.
// Wave w: m-tile mt=w>>1, d-half dhalf=w&1 (4 n-tiles). LN needs full d=128
// per row -> cross-wave combine via tiny LDS buffer.
// All global loads/stores wave-contiguous.
// -------------------------------------------------------------------------
__global__ __launch_bounds__(256, 2) void lin_ln_silu_kernel(
    const float* __restrict__ s, const float* __restrict__ W1,
    const float* __restrict__ b1, unsigned short* __restrict__ hfrag) {
  __shared__ unsigned short afr[2 * 4 * 512];  // [mt][ks][lane*8+e]  8 KB
  __shared__ unsigned short bfr[8 * 4 * 512];  // [nt][ks][lane*8+e] 32 KB
  __shared__ unsigned short trans[128 * 34];   // [d][n_local], pad 34
  __shared__ float lnb[2][32][2];              // [dhalf][row][s1,s2]
  const int t = threadIdx.x;
  const int n0 = blockIdx.x * 32;
  const int b = blockIdx.y;
  const int lane = t & 63;
  const int w = t >> 6;
  const int l15 = lane & 15;
  const int quad = lane >> 4;

  // stage s tile (32 x 128 fp32) -> afr, chunk-linear coalesced
#pragma unroll
  for (int rep = 0; rep < 4; ++rep) {
    int q = t + 256 * rep;  // 0..1023
    int n = q >> 5, k = (q & 31) * 4;
    float4 v = *reinterpret_cast<const float4*>(
        s + ((size_t)(b * N_ + n0 + n)) * H_ + k);
    short4v sv;
    sv.x = (short)f2bf(v.x); sv.y = (short)f2bf(v.y);
    sv.z = (short)f2bf(v.z); sv.w = (short)f2bf(v.w);
    int mt = n >> 4, ks = k >> 5, qd = (k >> 3) & 3, e0 = k & 7;
    *reinterpret_cast<short4v*>(
        &afr[((mt * 4 + ks) * 64 + qd * 16 + (n & 15)) * 8 + e0]) = sv;
  }
  // stage W1 (128 x 128 fp32) -> bfr
#pragma unroll
  for (int rep = 0; rep < 16; ++rep) {
    int q = t + 256 * rep;  // 0..4095
    int d = q >> 5, k = (q & 31) * 4;
    float4 v = *reinterpret_cast<const float4*>(W1 + (size_t)d * H_ + k);
    short4v sv;
    sv.x = (short)f2bf(v.x); sv.y = (short)f2bf(v.y);
    sv.z = (short)f2bf(v.z); sv.w = (short)f2bf(v.w);
    int nt = d >> 4, ks = k >> 5, qd = (k >> 3) & 3, e0 = k & 7;
    *reinterpret_cast<short4v*>(
        &bfr[((nt * 4 + ks) * 64 + qd * 16 + (d & 15)) * 8 + e0]) = sv;
  }
  __syncthreads();

  const int mt = w >> 1, dhalf = w & 1;
  f32x4 acc[4];
#pragma unroll
  for (int nt2 = 0; nt2 < 4; ++nt2)
#pragma unroll
    for (int e = 0; e < 4; ++e) acc[nt2][e] = 0.f;

#pragma unroll
  for (int ks = 0; ks < 4; ++ks) {
    short8 av =
        *reinterpret_cast<const short8*>(&afr[((mt * 4 + ks) * 64 + lane) * 8]);
#pragma unroll
    for (int nt2 = 0; nt2 < 4; ++nt2) {
      short8 bv = *reinterpret_cast<const short8*>(
          &bfr[(((dhalf * 4 + nt2) * 4 + ks) * 64 + lane) * 8]);
      acc[nt2] =
          __builtin_amdgcn_mfma_f32_16x16x32_bf16(av, bv, acc[nt2], 0, 0, 0);
    }
  }

  float bb[4];
#pragma unroll
  for (int nt2 = 0; nt2 < 4; ++nt2)
    bb[nt2] = b1[dhalf * 64 + nt2 * 16 + l15];

  // per-row partial sums over this wave's 64 d's
#pragma unroll
  for (int rr = 0; rr < 4; ++rr) {
    float s1 = 0.f, s2 = 0.f;
#pragma unroll
    for (int nt2 = 0; nt2 < 4; ++nt2) {
      float x = acc[nt2][rr] + bb[nt2];
      acc[nt2][rr] = x;
      s1 += x;
      s2 += x * x;
    }
#pragma unroll
    for (int off = 8; off >= 1; off >>= 1) {
      s1 += __shfl_xor(s1, off);
      s2 += __shfl_xor(s2, off);
    }
    int row = mt * 16 + quad * 4 + rr;
    if (l15 == 0) {
      lnb[dhalf][row][0] = s1;
      lnb[dhalf][row][1] = s2;
    }
  }
  __syncthreads();

  // combine halves, normalize, silu, write transpose buffer
#pragma unroll
  for (int rr = 0; rr < 4; ++rr) {
    int row = mt * 16 + quad * 4 + rr;
    float s1 = lnb[0][row][0] + lnb[1][row][0];
    float s2 = lnb[0][row][1] + lnb[1][row][1];
    float mean = s1 * (1.f / 128.f);
    float var = s2 * (1.f / 128.f) - mean * mean;
    float rs = rsqrtf(var + 1e-5f);
#pragma unroll
    for (int nt2 = 0; nt2 < 4; ++nt2) {
      float x = (acc[nt2][rr] - mean) * rs;
      float y = x / (1.f + __expf(-x));  // silu
      trans[(dhalf * 64 + nt2 * 16 + l15) * 34 + row] = f2bf(y);
    }
  }
  __syncthreads();

  // frag-major store: chunk q = (d, k2): 8 consecutive j = one 16B frag piece
#pragma unroll
  for (int rep = 0; rep < 2; ++rep) {
    int q = t + 256 * rep;  // 0..511
    int d = q >> 2, k2 = q & 3;
    short8 v = *reinterpret_cast<const short8*>(&trans[d * 34 + k2 * 8]);
    int n = n0 + k2 * 8;
    int KS = n >> 5, q16 = (n >> 3) & 3;
    *reinterpret_cast<short8*>(
        hfrag + (size_t)b * 65536 +
        (size_t)(((d >> 4) * 16 + KS) * 64 + q16 * 16 + (d & 15)) * 8) = v;
  }
}

// -------------------------------------------------------------------------
// Kernel 2: v[b,i,c,d] = sum_j mask*ev*h via MFMA.
// Grid (i-tiles 32, dh 2, b 32) = 2048 blocks, 128 thr (2 waves).
// Twins (dh 0/1) are 32 apart in linear id -> same XCD -> ev/mask L2 dedup
// (verified R4: FETCH ~= compulsory).
// Per 64-j round: ev staged CHUNK-LINEAR (each wave-load = contiguous 16B/
// lane, full line utilization), mask via L1-hot scalars, de-interleaved into
// A-frag-major LDS ph[c][ks][lane][e]. B-frags: ONE contiguous 1KB global
// load each from frag-major hfrag (no LDS). 12 MFMA / wave / round.
// LDS 6 KB, target 5 waves/SIMD -> ~10 de-phased barrier domains per CU.
// -------------------------------------------------------------------------
__global__ __launch_bounds__(128, 5) void cfconv_mfma_kernel(
    const float* __restrict__ ev, const float* __restrict__ mask,
    const unsigned short* __restrict__ hfrag, float* __restrict__ out) {
  __shared__ unsigned short ph[3 * 2 * 512];  // [c][ks][lane*8+e]  6 KB
  const int t = threadIdx.x;
  const int i0 = blockIdx.x * 16;
  const int dh4 = blockIdx.y * 4;  // NT base
  const int b = blockIdx.z;
  const int lane = t & 63;
  const int w = t >> 6;
  const int l15 = lane & 15;
  const int quad = lane >> 4;

  const float* evb = ev + (size_t)(b * N_ + i0) * N_ * 3;
  const float* mb = mask + (size_t)(b * N_ + i0) * N_;
  const unsigned short* hfb = hfrag + (size_t)b * 65536;

  f32x4 acc[3][2];
#pragma unroll
  for (int c = 0; c < 3; ++c)
#pragma unroll
    for (int p = 0; p < 2; ++p)
#pragma unroll
      for (int e = 0; e < 4; ++e) acc[c][p][e] = 0.f;

  for (int r = 0; r < 8; ++r) {
    const int j0 = r * 64;
    if (r) __syncthreads();  // all waves done reading ph before overwrite

    // stage ev*mask -> ph. 768 chunks (16 rows x 48): chunk = 4 consecutive
    // floats of one ev row (16B/lane, wave-contiguous within rows).
#pragma unroll
    for (int rep = 0; rep < 6; ++rep) {
      int ch = t + 128 * rep;  // 0..767
      int i = ch / 48;
      int f0 = (ch % 48) * 4;  // within-row float offset (0..188)
      float4 e4 = *reinterpret_cast<const float4*>(
          evb + ((size_t)i * N_ + j0) * 3 + f0);
      int jl0 = f0 / 3;  // the 4 floats span exactly j = jl0, jl0+1
      float mlo = mb[(size_t)i * N_ + j0 + jl0];
      float mhi = mb[(size_t)i * N_ + j0 + jl0 + 1];
      float fe[4] = {e4.x, e4.y, e4.z, e4.w};
#pragma unroll
      for (int e = 0; e < 4; ++e) {
        int f = f0 + e;
        int j = f / 3;          // local j 0..63
        int c = f - j * 3;      // channel
        float m = (j == jl0) ? mlo : mhi;
        ph[c * 1024 + (j >> 5) * 512 + ((j >> 3) & 3) * 128 + i * 8 +
           (j & 7)] = f2bf(fe[e] * m);
      }
    }
    __syncthreads();

    // compute: 2 k-slabs x (3 c-tiles x 2 d-tiles per wave)
#pragma unroll
    for (int ks = 0; ks < 2; ++ks) {
      short8 av[3];
#pragma unroll
      for (int c = 0; c < 3; ++c)
        av[c] = *reinterpret_cast<const short8*>(
            &ph[(c * 2 + ks) * 512 + lane * 8]);
#pragma unroll
      for (int p = 0; p < 2; ++p) {
        const int NT = dh4 + w * 2 + p;
        short8 bv = *reinterpret_cast<const short8*>(
            hfb + (size_t)((NT * 16 + r * 2 + ks) * 64 + lane) * 8);
#pragma unroll
        for (int c = 0; c < 3; ++c)
          acc[c][p] = __builtin_amdgcn_mfma_f32_16x16x32_bf16(av[c], bv,
                                                              acc[c][p], 0, 0, 0);
      }
    }
  }

  // epilogue: C/D layout col=lane&15 (d_local), row=quad*4+reg (i_local)
#pragma unroll
  for (int c = 0; c < 3; ++c)
#pragma unroll
    for (int p = 0; p < 2; ++p) {
      const int d = (dh4 + w * 2 + p) * 16 + l15;
#pragma unroll
      for (int rr = 0; rr < 4; ++rr) {
        const int i = i0 + quad * 4 + rr;
        out[(((size_t)b * N_ + i) * 3 + c) * H_ + d] = acc[c][p][rr];
      }
    }
}

extern "C" void kernel_launch(void* const* d_in, const int* in_sizes, int n_in,
                              void* d_out, int out_size, void* d_ws,
                              size_t ws_size, hipStream_t stream) {
  const float* s = (const float*)d_in[0];
  const float* ev = (const float*)d_in[1];
  const float* mask = (const float*)d_in[2];
  const float* W1 = (const float*)d_in[3];
  const float* b1 = (const float*)d_in[4];
  float* out = (float*)d_out;
  unsigned short* hfrag = (unsigned short*)d_ws;  // 4 MB frag-major bf16

  lin_ln_silu_kernel<<<dim3(N_ / 32, B_), 256, 0, stream>>>(s, W1, b1, hfrag);
  cfconv_mfma_kernel<<<dim3(N_ / 16, 2, B_), 128, 0, stream>>>(ev, mask, hfrag,
                                                               out);
}